// Round 8
// baseline (314.628 us; speedup 1.0000x reference)
//
#include <hip/hip_runtime.h>
#include <math.h>

// RBF-kernel causal attention (gfx950), round 12.
// Prepass: K -> f16 row-major + ksq(=s*|k|^2); V -> bf16 transposed
//          tile-contiguous Vt[bh][jt][128d][64j]. All fully coalesced.
// Main (v12 = v11 repackaged): ZERO LDS, ZERO barriers. R4/R5 showed the
//          barrier-locked staging (not the LDS pipe) was binding. KV/bh =
//          1MB; 4 bh per XCD = 4MB = L2 -> read K/V/ksq fragments DIRECTLY
//          from global (don't stage what cache-fits). Fragment reads are
//          line-coalesced (64 lanes = 16 rows x one 64B line).
//          v11 used single-wave 64-thread blocks and hit two consecutive
//          container failures; v12 packs 4 INDEPENDENT waves (no barrier)
//          into a conventional 256-thread block (the launch shape every
//          working kernel here used): wave w owns q-tile y=4*blockIdx.y+w.
//          P stays in registers via permlane transpose + cvt_pk.
//          Plain __launch_bounds__(256): R5 precedent, no spills.

#define NSEQ 2048
#define DH   128
#define BHC  32
#define SM_SCALE 0.08838834764831845f

typedef __attribute__((ext_vector_type(8))) short    short8;   // bf16x8
typedef __attribute__((ext_vector_type(8))) _Float16 half8;    // f16x8
typedef __attribute__((ext_vector_type(4))) short    short4_;
typedef __attribute__((ext_vector_type(4))) float    float4_;
typedef __attribute__((ext_vector_type(4))) unsigned uint4_;
typedef __attribute__((ext_vector_type(2))) unsigned uint2_;

__device__ __forceinline__ short f2bf(float x){
  union{float f; unsigned u;} a; a.f=x;
  unsigned r = a.u + 0x7fffu + ((a.u>>16)&1u);   // RNE
  return (short)(r>>16);
}
__device__ __forceinline__ float bf2f(short h){
  union{float f; unsigned u;} a; a.u=((unsigned)(unsigned short)h)<<16; return a.f;
}
__device__ __forceinline__ unsigned packbf(float a, float b){
  return (unsigned)(unsigned short)f2bf(a) | ((unsigned)(unsigned short)f2bf(b)<<16);
}
__device__ __forceinline__ unsigned cvtpk_bf16(float a, float b){
  unsigned r;
  asm("v_cvt_pk_bf16_f32 %0, %1, %2" : "=v"(r) : "v"(a), "v"(b));
  return r;   // lo16 = bf16(a), hi16 = bf16(b), RNE
}

// (X,Y) = cross-32-lane half swap
__device__ __forceinline__ void qswap32(unsigned A, unsigned B, unsigned &X, unsigned &Y){
  uint2_ r = __builtin_amdgcn_permlane32_swap(A, B, false, false);
  X = r[0]; Y = r[1];
}
// (X,Y) = odd/even 16-row swap
__device__ __forceinline__ void qswap16(unsigned A, unsigned B, unsigned &X, unsigned &Y, int oddq){
#if __has_builtin(__builtin_amdgcn_permlane16_swap)
  uint2_ r = __builtin_amdgcn_permlane16_swap(A, B, false, false);
  X = r[0]; Y = r[1];
#else
  unsigned As = (unsigned)__builtin_amdgcn_ds_swizzle((int)A, 0x401F); // xor lane^16
  unsigned Bs = (unsigned)__builtin_amdgcn_ds_swizzle((int)B, 0x401F);
  X = oddq ? Bs : A;
  Y = oddq ? B  : As;
#endif
}

// ---------------- prepass ----------------
__global__ __launch_bounds__(256)
void prep_kv5(const float* __restrict__ kg, const float* __restrict__ vg,
              _Float16* __restrict__ khg, short* __restrict__ vtg,
              float* __restrict__ ksqg){
  __shared__ unsigned Vls[128*33];   // [d][j2] short2-pairs, stride 33 dw
  const int b = blockIdx.x, t = threadIdx.x;
  const int l = t & 63, wv = t >> 6;
  if(b < 1024){
    // ---- V tile (bh, jt): fp32 rows -> bf16 V^T tile-contiguous ----
    const int bh = b>>5, jt = b&31;
    const float4_* vb4 = (const float4_*)(vg + ((size_t)bh*NSEQ + (size_t)jt*64)*DH);
    #pragma unroll
    for(int i=0;i<8;++i){
      float4_ own = vb4[i*256 + t];
      float4_ par;
      par.x = __shfl_xor(own.x, 32); par.y = __shfl_xor(own.y, 32);
      par.z = __shfl_xor(own.z, 32); par.w = __shfl_xor(own.w, 32);
      const int hi = (l>>5)&1;           // row-parity bit
      unsigned w0 = hi ? packbf(par.z, own.z) : packbf(own.x, par.x);
      unsigned w1 = hi ? packbf(par.w, own.w) : packbf(own.y, par.y);
      const int dd = 4*(t&31) + 2*hi;
      const int j2 = 4*i + wv;           // row-pair index
      Vls[dd*33 + j2]     = w0;
      Vls[(dd+1)*33 + j2] = w1;
    }
    __syncthreads();
    short* outp = vtg + ((size_t)(bh*32 + jt)*DH)*64;
    #pragma unroll
    for(int it=0; it<4; ++it){
      int idx = t + 256*it;              // 0..1023
      int d = idx>>3, slot = idx&7;
      uint4_ o;
      o.x = Vls[d*33 + 4*slot];   o.y = Vls[d*33 + 4*slot+1];
      o.z = Vls[d*33 + 4*slot+2]; o.w = Vls[d*33 + 4*slot+3];
      *(uint4_*)(outp + d*64 + 8*slot) = o;
    }
  } else {
    // ---- K: fp32 -> f16 row-major + ksq ----
    const int kb = b - 1024;             // 64 rows per block
    const float4_* kb4 = (const float4_*)(kg + (size_t)kb*64*DH);
    #pragma unroll
    for(int i=0;i<8;++i){
      float4_ x = kb4[i*256 + t];        // row = 64kb + 8i + (t>>5), d = 4*(t&31)
      const int row = 64*kb + 8*i + (t>>5);
      const int d   = 4*(t&31);
      union{ _Float16 h[4]; uint2_ u; } pk;
      pk.h[0]=(_Float16)x.x; pk.h[1]=(_Float16)x.y;
      pk.h[2]=(_Float16)x.z; pk.h[3]=(_Float16)x.w;
      *(uint2_*)(khg + (size_t)row*DH + d) = pk.u;
      float ss = x.x*x.x + x.y*x.y + x.z*x.z + x.w*x.w;
      ss += __shfl_xor(ss,1);  ss += __shfl_xor(ss,2);
      ss += __shfl_xor(ss,4);  ss += __shfl_xor(ss,8);
      ss += __shfl_xor(ss,16);
      if((l&31)==0) ksqg[row] = SM_SCALE*ss;
    }
  }
}

// ---------------- main kernel (v12): no LDS, no barriers, 4 indep waves ----------------
__global__ __launch_bounds__(256)
void rbf_attn12(const float* __restrict__ qg,
                const _Float16* __restrict__ khg,
                const short* __restrict__ vtg,
                const float* __restrict__ ksqg,
                float* __restrict__ og){
  const int tid = threadIdx.x;
  const int w = tid>>6, l = tid&63;      // wave id, lane
  const int quad=l>>4, lr=l&15;
  const int bh = blockIdx.x;
  const int y  = blockIdx.y*4 + w;       // 0..63, big tiles first
  const int qbase = 2016 - 32*y;         // wave owns q-rows [qbase, qbase+32)
  const int jtmax = (qbase + 31) >> 6;

  const float*    Qg = qg   + (size_t)bh*NSEQ*DH;
  const _Float16* Kh = khg  + (size_t)bh*NSEQ*DH;
  const short*    Vt = vtg  + (size_t)bh*32*DH*64;
  const float*    Ks = ksqg + (size_t)bh*NSEQ;
  float*          Og = og   + (size_t)bh*NSEQ*DH;

  // ---- Q -> f16 B-fragments (once) + qsq, both row-fragments ----
  half8 qf[2][4];
  float qsq[2];
  #pragma unroll
  for(int rt=0;rt<2;++rt){
    const int qrow = qbase + 16*rt + lr;
    const float* qp = Qg + (size_t)qrow*DH + 8*quad;
    float ss=0.f;
    #pragma unroll
    for(int ks=0;ks<4;++ks){
      float4_ a = *(const float4_*)(qp + 32*ks);
      float4_ b = *(const float4_*)(qp + 32*ks + 4);
      half8 h;
      #pragma unroll
      for(int j=0;j<4;++j){
        h[j]   = (_Float16)a[j];
        h[j+4] = (_Float16)b[j];
        ss += a[j]*a[j] + b[j]*b[j];
      }
      qf[rt][ks]=h;
    }
    ss += __shfl_xor(ss,16);
    ss += __shfl_xor(ss,32);
    qsq[rt] = SM_SCALE*ss;
  }

  float4_ oacc[2][8];
  #pragma unroll
  for(int a=0;a<2;++a)
    #pragma unroll
    for(int b2=0;b2<8;++b2) oacc[a][b2] = (float4_)0.f;

  const _Float16* Kt  = Kh;              // K rows of tile jt
  const short*    Vj  = Vt;              // V^T tile jt
  const float*    Ksj = Ks;              // ksq of tile jt

  for(int jt=0; jt<=jtmax; ++jt){
    const int rel = qbase + 31 - 64*jt;          // >= 0 by jtmax
    const int ctmax = (rel>>4) < 3 ? (rel>>4) : 3;
    const int nks2  = (rel >= 32) ? 2 : 1;

    // ---- S^T = K . Q^T (f16), K fragments straight from global/L2 ----
    float4_ sacc[2][4];
    #pragma unroll
    for(int a=0;a<2;++a)
      #pragma unroll
      for(int ct=0;ct<4;++ct) sacc[a][ct] = (float4_)0.f;

    #pragma unroll
    for(int ks=0;ks<4;++ks){
      half8 kf[4];
      #pragma unroll
      for(int ct=0;ct<4;++ct)
        if(ct<=ctmax) kf[ct] = *(const half8*)(Kt + (size_t)(16*ct+lr)*DH + 32*ks + 8*quad);
      __builtin_amdgcn_s_setprio(1);
      #pragma unroll
      for(int ct=0;ct<4;++ct)
        if(ct<=ctmax){
          sacc[0][ct]=__builtin_amdgcn_mfma_f32_16x16x32_f16(kf[ct],qf[0][ks],sacc[0][ct],0,0,0);
          sacc[1][ct]=__builtin_amdgcn_mfma_f32_16x16x32_f16(kf[ct],qf[1][ks],sacc[1][ct],0,0,0);
        }
      __builtin_amdgcn_s_setprio(0);
    }

    // ---- exp -> packed bf16 P in registers ----
    unsigned pk[2][4][2];
    if(rel >= 94){
      // whole tile unmasked for every q-row of this wave
      #pragma unroll
      for(int ct=0;ct<4;++ct){
        float4_ kq = *(const float4_*)(Ksj + 16*ct + 4*quad);
        #pragma unroll
        for(int rt=0;rt<2;++rt){
          float p[4];
          #pragma unroll
          for(int r=0;r<4;++r)
            p[r] = __expf((2.f*SM_SCALE)*sacc[rt][ct][r] - qsq[rt] - kq[r]);
          pk[rt][ct][0] = cvtpk_bf16(p[0], p[1]);
          pk[rt][ct][1] = cvtpk_bf16(p[2], p[3]);
        }
      }
    } else {
      const int jg0 = 64*jt;
      #pragma unroll
      for(int ct=0;ct<4;++ct){
        if(ct < 2*nks2){
          float4_ kq = *(const float4_*)(Ksj + 16*ct + 4*quad);
          const int j0 = jg0 + 16*ct + 4*quad;
          #pragma unroll
          for(int rt=0;rt<2;++rt){
            const int qrow = qbase + 16*rt + lr;
            float p[4];
            #pragma unroll
            for(int r=0;r<4;++r){
              float logit = (2.f*SM_SCALE)*sacc[rt][ct][r] - qsq[rt] - kq[r];
              p[r] = (j0 + r <= qrow) ? __expf(logit) : 0.f;
            }
            pk[rt][ct][0] = cvtpk_bf16(p[0], p[1]);
            pk[rt][ct][1] = cvtpk_bf16(p[2], p[3]);
          }
        }
      }
    }

    // ---- O += P . V (in-register P transpose; V straight from global/L2) ----
    #pragma unroll
    for(int ks2=0;ks2<2;++ks2){
      if(ks2 < nks2){
        short8 pf[2];
        #pragma unroll
        for(int rt=0;rt<2;++rt){
          unsigned A0,B0,A1,B1;
          qswap32(pk[rt][2*ks2][0], pk[rt][2*ks2+1][0], A0, B0);
          qswap32(pk[rt][2*ks2][1], pk[rt][2*ks2+1][1], A1, B1);
          unsigned w0,w1,w2,w3;
          qswap16(A0, B0, w0, w2, quad&1);
          qswap16(A1, B1, w1, w3, quad&1);
          union{ uint4_ u; short8 s; } pfu;
          pfu.u.x=w0; pfu.u.y=w1; pfu.u.z=w2; pfu.u.w=w3;
          pf[rt] = pfu.s;   // = P[q=lr][j=32ks2+8quad+e], bf16
        }
        #pragma unroll
        for(int ctv=0;ctv<8;++ctv){
          const short8 vf = *(const short8*)(Vj + (size_t)(16*ctv+lr)*64 + 32*ks2 + 8*quad);
          __builtin_amdgcn_s_setprio(1);
          oacc[0][ctv]=__builtin_amdgcn_mfma_f32_16x16x32_bf16(pf[0],vf,oacc[0][ctv],0,0,0);
          oacc[1][ctv]=__builtin_amdgcn_mfma_f32_16x16x32_bf16(pf[1],vf,oacc[1][ctv],0,0,0);
          __builtin_amdgcn_s_setprio(0);
        }
      }
    }

    Kt  += 64*DH;      // next K tile (64 rows)
    Vj  += DH*64;      // next V^T tile
    Ksj += 64;
  }

  // ---- store O ----
  #pragma unroll
  for(int rt=0;rt<2;++rt)
    #pragma unroll
    for(int ctv=0;ctv<8;++ctv)
      #pragma unroll
      for(int r=0;r<4;++r){
        const int qrow = qbase + 16*rt + 4*quad + r;
        Og[(size_t)qrow*DH + 16*ctv + lr] = oacc[rt][ctv][r];
      }
}

// ---------------- fallback (no-workspace path, verified R2 kernel) ----------------
#define KSTf 136
#define VSTf 36
#define PSTf 72

__global__ __launch_bounds__(256,2)
void rbf_attn_mfma(const float* __restrict__ qg, const float* __restrict__ kg,
                   const float* __restrict__ vg, float* __restrict__ og){
  __shared__ short    Khi[64*KSTf];
  __shared__ short    Klo[64*KSTf];
  __shared__ unsigned VP [128*VSTf];
  __shared__ short    Pfb[64*PSTf];
  __shared__ float    qsq_s[64];
  __shared__ float    ksq_s[64];

  const int tid=threadIdx.x;
  const int w=tid>>6, l=tid&63;
  const int wr=w>>1, wc=w&1;
  const int quad=l>>4, lr=l&15;
  const int bh=blockIdx.x, yp=blockIdx.y;

  const float* Qg = qg + (size_t)bh*NSEQ*DH;
  const float* Kg = kg + (size_t)bh*NSEQ*DH;
  const float* Vg = vg + (size_t)bh*NSEQ*DH;
  float*       Og = og + (size_t)bh*NSEQ*DH;

  for(int pass=0;pass<2;++pass){
    const int m = pass ? (31-yp) : yp;
    __syncthreads();
    short8 qhf[2][4], qlf[2][4];
    #pragma unroll
    for(int rt=0;rt<2;++rt){
      const int grow = m*64 + 32*wr + 16*rt + lr;
      const float* qp = Qg + (size_t)grow*DH + 8*quad;
      float ss=0.f;
      #pragma unroll
      for(int ks=0;ks<4;++ks){
        float4_ a = *(const float4_*)(qp + 32*ks);
        float4_ b = *(const float4_*)(qp + 32*ks + 4);
        short8 hi, lo;
        #pragma unroll
        for(int j=0;j<4;++j){
          float fa=a[j], fb=b[j];
          short ha=f2bf(fa); hi[j]=ha;   lo[j]=f2bf(fa-bf2f(ha));
          short hb=f2bf(fb); hi[j+4]=hb; lo[j+4]=f2bf(fb-bf2f(hb));
          ss += fa*fa + fb*fb;
        }
        qhf[rt][ks]=hi; qlf[rt][ks]=lo;
      }
      ss += __shfl_xor(ss,16);
      ss += __shfl_xor(ss,32);
      if(wc==0 && quad==0) qsq_s[32*wr+16*rt+lr] = SM_SCALE*ss;
    }
    float4_ oacc[2][4];
    #pragma unroll
    for(int a=0;a<2;++a)
      #pragma unroll
      for(int b=0;b<4;++b) oacc[a][b] = (float4_)0.f;

    const int ntiles = m+1;
    for(int jt=0;jt<ntiles;++jt){
      const int jc = jt*64;
      __syncthreads();
      #pragma unroll
      for(int it=0;it<4;++it){
        const int i = tid + 256*it;
        const int row = i>>4, c0 = 8*(i&15);
        const float* kp = Kg + (size_t)(jc+row)*DH + c0;
        float4_ a = *(const float4_*)kp;
        float4_ b = *(const float4_*)(kp+4);
        short8 hi, lo;
        float ss=0.f;
        #pragma unroll
        for(int j=0;j<4;++j){
          float fa=a[j], fb=b[j];
          short ha=f2bf(fa); hi[j]=ha;   lo[j]=f2bf(fa-bf2f(ha));
          short hb=f2bf(fb); hi[j+4]=hb; lo[j+4]=f2bf(fb-bf2f(hb));
          ss += fa*fa + fb*fb;
        }
        ss += __shfl_xor(ss,1); ss += __shfl_xor(ss,2);
        ss += __shfl_xor(ss,4); ss += __shfl_xor(ss,8);
        if(lr==0) ksq_s[row] = SM_SCALE*ss;
        *(short8*)&Khi[row*KSTf + c0] = hi;
        *(short8*)&Klo[row*KSTf + c0] = lo;
      }
      #pragma unroll
      for(int it=0;it<4;++it){
        const int u = tid + 256*it;
        const int d = u & 127, jg = u >> 7;
        const float* vp = Vg + (size_t)(jc + 8*jg)*DH + d;
        float vv[8];
        #pragma unroll
        for(int jj=0;jj<8;++jj) vv[jj] = vp[(size_t)jj*DH];
        uint4_ pk;
        #pragma unroll
        for(int p2=0;p2<4;++p2)
          pk[p2] = (unsigned)(unsigned short)f2bf(vv[2*p2]) |
                   ((unsigned)(unsigned short)f2bf(vv[2*p2+1])<<16);
        *(uint4_*)&VP[d*VSTf + 4*jg] = pk;
      }
      __syncthreads();
      float4_ sacc[2][2];
      #pragma unroll
      for(int a=0;a<2;++a)
        #pragma unroll
        for(int b=0;b<2;++b) sacc[a][b] = (float4_)0.f;
      #pragma unroll
      for(int ks=0;ks<4;++ks){
        short8 khf[2], klf[2];
        #pragma unroll
        for(int ct=0;ct<2;++ct){
          const int off = (32*wc + 16*ct + lr)*KSTf + 32*ks + 8*quad;
          khf[ct] = *(const short8*)&Khi[off];
          klf[ct] = *(const short8*)&Klo[off];
        }
        #pragma unroll
        for(int rt=0;rt<2;++rt)
          #pragma unroll
          for(int ct=0;ct<2;++ct){
            sacc[rt][ct]=__builtin_amdgcn_mfma_f32_16x16x32_bf16(qhf[rt][ks],khf[ct],sacc[rt][ct],0,0,0);
            sacc[rt][ct]=__builtin_amdgcn_mfma_f32_16x16x32_bf16(qhf[rt][ks],klf[ct],sacc[rt][ct],0,0,0);
            sacc[rt][ct]=__builtin_amdgcn_mfma_f32_16x16x32_bf16(qlf[rt][ks],khf[ct],sacc[rt][ct],0,0,0);
          }
      }
      #pragma unroll
      for(int rt=0;rt<2;++rt){
        float qs[4];
        #pragma unroll
        for(int r=0;r<4;++r) qs[r]=qsq_s[32*wr+16*rt+4*quad+r];
        #pragma unroll
        for(int ct=0;ct<2;++ct){
          const float ksq = ksq_s[32*wc+16*ct+lr];
          const int colg = jc + 32*wc+16*ct+lr;
          #pragma unroll
          for(int r=0;r<4;++r){
            const int rowg = m*64 + 32*wr+16*rt+4*quad+r;
            float logit = (2.f*SM_SCALE)*sacc[rt][ct][r] - qs[r] - ksq;
            float p = (colg<=rowg)? __expf(logit) : 0.f;
            Pfb[(32*wr+16*rt+4*quad+r)*PSTf + 32*wc+16*ct+lr] = f2bf(p);
          }
        }
      }
      __syncthreads();
      #pragma unroll
      for(int ks2=0;ks2<2;++ks2){
        short8 pf[2];
        #pragma unroll
        for(int rt=0;rt<2;++rt)
          pf[rt] = *(const short8*)&Pfb[(32*wr+16*rt+lr)*PSTf + 32*ks2 + 8*quad];
        #pragma unroll
        for(int ctv=0;ctv<4;++ctv){
          const int d = 64*wc + 16*ctv + lr;
          const short8 vfb = *(const short8*)((const short*)VP + d*(2*VSTf) + 32*ks2 + 8*quad);
          #pragma unroll
          for(int rt=0;rt<2;++rt)
            oacc[rt][ctv]=__builtin_amdgcn_mfma_f32_16x16x32_bf16(pf[rt],vfb,oacc[rt][ctv],0,0,0);
        }
      }
    }
    #pragma unroll
    for(int rt=0;rt<2;++rt)
      #pragma unroll
      for(int ctv=0;ctv<4;++ctv)
        #pragma unroll
        for(int r=0;r<4;++r){
          const int rowg = m*64 + 32*wr + 16*rt + 4*quad + r;
          Og[(size_t)rowg*DH + 64*wc + 16*ctv + lr] = oacc[rt][ctv][r];
        }
  }
}

extern "C" void kernel_launch(void* const* d_in, const int* in_sizes, int n_in,
                              void* d_out, int out_size, void* d_ws, size_t ws_size,
                              hipStream_t stream) {
  const float* q = (const float*)d_in[0];
  const float* k = (const float*)d_in[1];
  const float* v = (const float*)d_in[2];
  float* out = (float*)d_out;

  const size_t nElem = (size_t)BHC*NSEQ*DH;            // 8.39M
  const size_t need  = nElem*2*sizeof(short) + (size_t)BHC*NSEQ*sizeof(float);

  if(ws_size >= need){
    _Float16* khg = (_Float16*)d_ws;
    short*    vtg = (short*)(khg + nElem);
    float*    ksqg = (float*)(vtg + nElem);
    prep_kv5<<<2048, 256, 0, stream>>>(k, v, khg, vtg, ksqg);
    rbf_attn12<<<dim3(BHC,16), 256, 0, stream>>>(q, khg, vtg, ksqg, out);
  } else {
    rbf_attn_mfma<<<dim3(BHC,16), 256, 0, stream>>>(q, k, v, out);
  }
}

// Round 9
// 193.128 us; speedup vs baseline: 1.6291x; 1.6291x over previous
//
#include <hip/hip_runtime.h>
#include <math.h>

// RBF-kernel causal attention (gfx950), round 13.
// Prepass: K -> f16 row-major + ksq(=s*|k|^2); V -> bf16 transposed
//          tile-contiguous Vt[bh][jt][128d][64j]. All fully coalesced.
// Main (v13 = v9 + swizzle + backfill): R8 falsified no-LDS streaming
//          (204us, all pipes idle -> L2 latency exposed); LDS staging +
//          reg prefetch is the right structure. v13 combines the three
//          measured wins: (1) v9 micro-kernel: 16 q-rows/wave, 4-wave
//          64-row blocks, in-register P transpose (permlane+cvt_pk),
//          (2) XOR-swizzled pad-free K/V LDS (KST=128, VST=64, granule
//          ^= row&7) -> conflict-free b128 reads/writes (kills 8.5M
//          conflict cycles), (3) 3-resident + backfill: LDS padded to
//          41,984B so only 3 blocks/CU fit while grid has 4 work/CU
//          (v6's accidental +10us win, now deliberate). Big tiles first.

#define NSEQ 2048
#define DH   128
#define BHC  32
#define SM_SCALE 0.08838834764831845f

typedef __attribute__((ext_vector_type(8))) short    short8;   // bf16x8
typedef __attribute__((ext_vector_type(8))) _Float16 half8;    // f16x8
typedef __attribute__((ext_vector_type(4))) short    short4_;
typedef __attribute__((ext_vector_type(4))) float    float4_;
typedef __attribute__((ext_vector_type(4))) unsigned uint4_;
typedef __attribute__((ext_vector_type(2))) unsigned uint2_;

__device__ __forceinline__ short f2bf(float x){
  union{float f; unsigned u;} a; a.f=x;
  unsigned r = a.u + 0x7fffu + ((a.u>>16)&1u);   // RNE
  return (short)(r>>16);
}
__device__ __forceinline__ float bf2f(short h){
  union{float f; unsigned u;} a; a.u=((unsigned)(unsigned short)h)<<16; return a.f;
}
__device__ __forceinline__ unsigned packbf(float a, float b){
  return (unsigned)(unsigned short)f2bf(a) | ((unsigned)(unsigned short)f2bf(b)<<16);
}
__device__ __forceinline__ unsigned cvtpk_bf16(float a, float b){
  unsigned r;
  asm("v_cvt_pk_bf16_f32 %0, %1, %2" : "=v"(r) : "v"(a), "v"(b));
  return r;   // lo16 = bf16(a), hi16 = bf16(b), RNE
}

// (X,Y) = cross-32-lane half swap
__device__ __forceinline__ void qswap32(unsigned A, unsigned B, unsigned &X, unsigned &Y){
  uint2_ r = __builtin_amdgcn_permlane32_swap(A, B, false, false);
  X = r[0]; Y = r[1];
}
// (X,Y) = odd/even 16-row swap
__device__ __forceinline__ void qswap16(unsigned A, unsigned B, unsigned &X, unsigned &Y, int oddq){
#if __has_builtin(__builtin_amdgcn_permlane16_swap)
  uint2_ r = __builtin_amdgcn_permlane16_swap(A, B, false, false);
  X = r[0]; Y = r[1];
#else
  unsigned As = (unsigned)__builtin_amdgcn_ds_swizzle((int)A, 0x401F); // xor lane^16
  unsigned Bs = (unsigned)__builtin_amdgcn_ds_swizzle((int)B, 0x401F);
  X = oddq ? Bs : A;
  Y = oddq ? B  : As;
#endif
}

// ---------------- prepass ----------------
__global__ __launch_bounds__(256)
void prep_kv5(const float* __restrict__ kg, const float* __restrict__ vg,
              _Float16* __restrict__ khg, short* __restrict__ vtg,
              float* __restrict__ ksqg){
  __shared__ unsigned Vls[128*33];   // [d][j2] short2-pairs, stride 33 dw
  const int b = blockIdx.x, t = threadIdx.x;
  const int l = t & 63, wv = t >> 6;
  if(b < 1024){
    // ---- V tile (bh, jt): fp32 rows -> bf16 V^T tile-contiguous ----
    const int bh = b>>5, jt = b&31;
    const float4_* vb4 = (const float4_*)(vg + ((size_t)bh*NSEQ + (size_t)jt*64)*DH);
    #pragma unroll
    for(int i=0;i<8;++i){
      float4_ own = vb4[i*256 + t];
      float4_ par;
      par.x = __shfl_xor(own.x, 32); par.y = __shfl_xor(own.y, 32);
      par.z = __shfl_xor(own.z, 32); par.w = __shfl_xor(own.w, 32);
      const int hi = (l>>5)&1;           // row-parity bit
      unsigned w0 = hi ? packbf(par.z, own.z) : packbf(own.x, par.x);
      unsigned w1 = hi ? packbf(par.w, own.w) : packbf(own.y, par.y);
      const int dd = 4*(t&31) + 2*hi;
      const int j2 = 4*i + wv;           // row-pair index
      Vls[dd*33 + j2]     = w0;
      Vls[(dd+1)*33 + j2] = w1;
    }
    __syncthreads();
    short* outp = vtg + ((size_t)(bh*32 + jt)*DH)*64;
    #pragma unroll
    for(int it=0; it<4; ++it){
      int idx = t + 256*it;              // 0..1023
      int d = idx>>3, slot = idx&7;
      uint4_ o;
      o.x = Vls[d*33 + 4*slot];   o.y = Vls[d*33 + 4*slot+1];
      o.z = Vls[d*33 + 4*slot+2]; o.w = Vls[d*33 + 4*slot+3];
      *(uint4_*)(outp + d*64 + 8*slot) = o;
    }
  } else {
    // ---- K: fp32 -> f16 row-major + ksq ----
    const int kb = b - 1024;             // 64 rows per block
    const float4_* kb4 = (const float4_*)(kg + (size_t)kb*64*DH);
    #pragma unroll
    for(int i=0;i<8;++i){
      float4_ x = kb4[i*256 + t];        // row = 64kb + 8i + (t>>5), d = 4*(t&31)
      const int row = 64*kb + 8*i + (t>>5);
      const int d   = 4*(t&31);
      union{ _Float16 h[4]; uint2_ u; } pk;
      pk.h[0]=(_Float16)x.x; pk.h[1]=(_Float16)x.y;
      pk.h[2]=(_Float16)x.z; pk.h[3]=(_Float16)x.w;
      *(uint2_*)(khg + (size_t)row*DH + d) = pk.u;
      float ss = x.x*x.x + x.y*x.y + x.z*x.z + x.w*x.w;
      ss += __shfl_xor(ss,1);  ss += __shfl_xor(ss,2);
      ss += __shfl_xor(ss,4);  ss += __shfl_xor(ss,8);
      ss += __shfl_xor(ss,16);
      if((l&31)==0) ksqg[row] = SM_SCALE*ss;
    }
  }
}

// ---------------- main kernel (v13) ----------------
// LDS: Kst 64x128 f16 (16KB, XOR-swizzled granules), Vst 128x64 bf16 (16KB,
// XOR-swizzled), ksLs oversized to 9216B as deliberate pad -> 41,984B total
// -> exactly 3 blocks/CU resident; grid 1024 = 4 work/CU -> backfill.
__global__ __launch_bounds__(256,2)
void rbf_attn13(const float* __restrict__ qg,
                const _Float16* __restrict__ khg,
                const short* __restrict__ vtg,
                const float* __restrict__ ksqg,
                float* __restrict__ og){
  __shared__ short Kst[64*128];     // 16384 B  (phys granule = g ^ (row&7))
  __shared__ short Vst[128*64];     // 16384 B  (phys granule = g ^ (d&7))
  __shared__ float ksLs[2304];      //  9216 B  (only [0..63] used; rest = pad)

  const int tid=threadIdx.x;
  const int w=tid>>6, l=tid&63;
  const int quad=l>>4, lr=l&15;
  const int bh=blockIdx.x;
  const int mq = 31 - blockIdx.y;        // big Q-tiles dispatch first
  const int qbase = 64*mq + 16*w;        // wave owns 16 q-rows

  const float*    Qg = qg   + (size_t)bh*NSEQ*DH;
  const _Float16* Kh = khg  + (size_t)bh*NSEQ*DH;
  const short*    Vt = vtg  + (size_t)bh*32*DH*64;
  const float*    Ks = ksqg + (size_t)bh*NSEQ;
  float*          Og = og   + (size_t)bh*NSEQ*DH;

  // ---- Q -> f16 B-fragments (once) + qsq ----
  half8 qf[4];
  float qsq;
  {
    const int qrow = qbase + lr;
    const float* qp = Qg + (size_t)qrow*DH + 8*quad;
    float ss=0.f;
    #pragma unroll
    for(int ks=0;ks<4;++ks){
      float4_ a = *(const float4_*)(qp + 32*ks);
      float4_ b = *(const float4_*)(qp + 32*ks + 4);
      half8 h;
      #pragma unroll
      for(int j=0;j<4;++j){
        h[j]   = (_Float16)a[j];
        h[j+4] = (_Float16)b[j];
        ss += a[j]*a[j] + b[j]*b[j];
      }
      qf[ks]=h;
    }
    ss += __shfl_xor(ss,16);
    ss += __shfl_xor(ss,32);
    qsq = SM_SCALE*ss;
  }

  float4_ oacc[8];
  #pragma unroll
  for(int b2=0;b2<8;++b2) oacc[b2] = (float4_)0.f;

  // ---- staging prefetch regs for jt=0 ----
  uint4_ kreg[4], vreg[4];
  float  kqreg = 0.f;
  {
    #pragma unroll
    for(int it=0;it<4;++it){
      int idx = tid + 256*it;
      int row = idx>>4, c = idx&15;
      kreg[it] = *(const uint4_*)(Kh + (size_t)row*DH + 8*c);
      int d = idx>>3, slot = idx&7;
      vreg[it] = *(const uint4_*)(Vt + (size_t)d*64 + 8*slot);
    }
    if(tid<64) kqreg = Ks[tid];
  }

  for(int jt=0; jt<=mq; ++jt){
    // ---- write staged regs -> LDS (XOR-swizzled granules) ----
    #pragma unroll
    for(int it=0;it<4;++it){
      int idx = tid + 256*it;
      int row = idx>>4, c = idx&15;
      *(uint4_*)&Kst[row*128 + 8*(c ^ (row&7))] = kreg[it];
      int d = idx>>3, slot = idx&7;
      *(uint4_*)&Vst[d*64 + 8*(slot ^ (d&7))] = vreg[it];
    }
    if(tid<64) ksLs[tid] = kqreg;
    __syncthreads();                       // B2: tile visible

    // ---- prefetch next tile -> regs ----
    if(jt < mq){
      const int jc2 = (jt+1)*64;
      #pragma unroll
      for(int it=0;it<4;++it){
        int idx = tid + 256*it;
        int row = idx>>4, c = idx&15;
        kreg[it] = *(const uint4_*)(Kh + (size_t)(jc2+row)*DH + 8*c);
        int d = idx>>3, slot = idx&7;
        vreg[it] = *(const uint4_*)(Vt + ((size_t)(jt+1)*DH + d)*64 + 8*slot);
      }
      if(tid<64) kqreg = Ks[jc2 + tid];
    }

    const bool diag = (jt == mq);
    const int ctmax = diag ? w : 3;              // QK tiles with any unmasked col
    const int nks2  = (diag && w < 2) ? 1 : 2;   // PV k-clusters with any P!=0

    // ---- S^T = K . Q^T (f16, single pass) ----
    float4_ sacc[4];
    #pragma unroll
    for(int ct=0;ct<4;++ct) sacc[ct] = (float4_)0.f;

    __builtin_amdgcn_s_setprio(1);
    #pragma unroll
    for(int ks=0;ks<4;++ks){
      half8 kf[4];
      #pragma unroll
      for(int ct=0;ct<4;++ct)
        if(ct<=ctmax)
          kf[ct] = *(const half8*)&Kst[(16*ct+lr)*128 + 8*((4*ks+quad) ^ (lr&7))];
      #pragma unroll
      for(int ct=0;ct<4;++ct)
        if(ct<=ctmax) sacc[ct]=__builtin_amdgcn_mfma_f32_16x16x32_f16(kf[ct],qf[ks],sacc[ct],0,0,0);
    }
    __builtin_amdgcn_s_setprio(0);

    // ---- exp -> packed bf16 P in registers ----
    // sacc[ct][r] = S^T[j=16ct+4*quad+r][q=lr]
    unsigned pk[4][2];
    {
      const int jg0 = 64*jt;
      const int qrow = qbase + lr;
      #pragma unroll
      for(int ct=0;ct<4;++ct){
        if(ct < 2*nks2){
          float4_ kq = *(const float4_*)&ksLs[16*ct + 4*quad];
          const int j0 = jg0 + 16*ct + 4*quad;
          float p[4];
          #pragma unroll
          for(int r=0;r<4;++r){
            float logit = (2.f*SM_SCALE)*sacc[ct][r] - qsq - kq[r];
            p[r] = (j0 + r <= qrow) ? __expf(logit) : 0.f;
          }
          pk[ct][0] = cvtpk_bf16(p[0], p[1]);
          pk[ct][1] = cvtpk_bf16(p[2], p[3]);
        }
      }
    }

    // ---- O += P . V (P transposed in-register via permlane swaps) ----
    __builtin_amdgcn_s_setprio(1);
    #pragma unroll
    for(int ks2=0;ks2<2;++ks2){
      if(ks2 < nks2){
        // stage 1: cross-half swap
        unsigned A0,B0,A1,B1;
        qswap32(pk[2*ks2][0], pk[2*ks2+1][0], A0, B0);
        qswap32(pk[2*ks2][1], pk[2*ks2+1][1], A1, B1);
        // stage 2: odd/even 16-row swap -> pf dwords
        unsigned w0,w1,w2,w3;
        qswap16(A0, B0, w0, w2, quad&1);
        qswap16(A1, B1, w1, w3, quad&1);
        union{ uint4_ u; short8 s; } pfu;
        pfu.u.x=w0; pfu.u.y=w1; pfu.u.z=w2; pfu.u.w=w3;
        const short8 pf = pfu.s;   // = P[q=lr][j=32ks2+8quad+e], bf16
        #pragma unroll
        for(int ctv=0;ctv<8;++ctv){
          const short8 vf = *(const short8*)&Vst[(16*ctv+lr)*64 + 8*((4*ks2+quad) ^ (lr&7))];
          oacc[ctv]=__builtin_amdgcn_mfma_f32_16x16x32_bf16(pf,vf,oacc[ctv],0,0,0);
        }
      }
    }
    __builtin_amdgcn_s_setprio(0);

    __syncthreads();                       // B1: reads done before overwrite
  }

  // ---- store O ----
  #pragma unroll
  for(int ctv=0;ctv<8;++ctv)
    #pragma unroll
    for(int r=0;r<4;++r){
      const int qrow = qbase + 4*quad + r;
      Og[(size_t)qrow*DH + 16*ctv + lr] = oacc[ctv][r];
    }
}

// ---------------- fallback (no-workspace path, verified R2 kernel) ----------------
#define KSTf 136
#define VSTf 36
#define PSTf 72

__global__ __launch_bounds__(256,2)
void rbf_attn_mfma(const float* __restrict__ qg, const float* __restrict__ kg,
                   const float* __restrict__ vg, float* __restrict__ og){
  __shared__ short    Khi[64*KSTf];
  __shared__ short    Klo[64*KSTf];
  __shared__ unsigned VP [128*VSTf];
  __shared__ short    Pfb[64*PSTf];
  __shared__ float    qsq_s[64];
  __shared__ float    ksq_s[64];

  const int tid=threadIdx.x;
  const int w=tid>>6, l=tid&63;
  const int wr=w>>1, wc=w&1;
  const int quad=l>>4, lr=l&15;
  const int bh=blockIdx.x, yp=blockIdx.y;

  const float* Qg = qg + (size_t)bh*NSEQ*DH;
  const float* Kg = kg + (size_t)bh*NSEQ*DH;
  const float* Vg = vg + (size_t)bh*NSEQ*DH;
  float*       Og = og + (size_t)bh*NSEQ*DH;

  for(int pass=0;pass<2;++pass){
    const int m = pass ? (31-yp) : yp;
    __syncthreads();
    short8 qhf[2][4], qlf[2][4];
    #pragma unroll
    for(int rt=0;rt<2;++rt){
      const int grow = m*64 + 32*wr + 16*rt + lr;
      const float* qp = Qg + (size_t)grow*DH + 8*quad;
      float ss=0.f;
      #pragma unroll
      for(int ks=0;ks<4;++ks){
        float4_ a = *(const float4_*)(qp + 32*ks);
        float4_ b = *(const float4_*)(qp + 32*ks + 4);
        short8 hi, lo;
        #pragma unroll
        for(int j=0;j<4;++j){
          float fa=a[j], fb=b[j];
          short ha=f2bf(fa); hi[j]=ha;   lo[j]=f2bf(fa-bf2f(ha));
          short hb=f2bf(fb); hi[j+4]=hb; lo[j+4]=f2bf(fb-bf2f(hb));
          ss += fa*fa + fb*fb;
        }
        qhf[rt][ks]=hi; qlf[rt][ks]=lo;
      }
      ss += __shfl_xor(ss,16);
      ss += __shfl_xor(ss,32);
      if(wc==0 && quad==0) qsq_s[32*wr+16*rt+lr] = SM_SCALE*ss;
    }
    float4_ oacc[2][4];
    #pragma unroll
    for(int a=0;a<2;++a)
      #pragma unroll
      for(int b=0;b<4;++b) oacc[a][b] = (float4_)0.f;

    const int ntiles = m+1;
    for(int jt=0;jt<ntiles;++jt){
      const int jc = jt*64;
      __syncthreads();
      #pragma unroll
      for(int it=0;it<4;++it){
        const int i = tid + 256*it;
        const int row = i>>4, c0 = 8*(i&15);
        const float* kp = Kg + (size_t)(jc+row)*DH + c0;
        float4_ a = *(const float4_*)kp;
        float4_ b = *(const float4_*)(kp+4);
        short8 hi, lo;
        float ss=0.f;
        #pragma unroll
        for(int j=0;j<4;++j){
          float fa=a[j], fb=b[j];
          short ha=f2bf(fa); hi[j]=ha;   lo[j]=f2bf(fa-bf2f(ha));
          short hb=f2bf(fb); hi[j+4]=hb; lo[j+4]=f2bf(fb-bf2f(hb));
          ss += fa*fa + fb*fb;
        }
        ss += __shfl_xor(ss,1); ss += __shfl_xor(ss,2);
        ss += __shfl_xor(ss,4); ss += __shfl_xor(ss,8);
        if(lr==0) ksq_s[row] = SM_SCALE*ss;
        *(short8*)&Khi[row*KSTf + c0] = hi;
        *(short8*)&Klo[row*KSTf + c0] = lo;
      }
      #pragma unroll
      for(int it=0;it<4;++it){
        const int u = tid + 256*it;
        const int d = u & 127, jg = u >> 7;
        const float* vp = Vg + (size_t)(jc + 8*jg)*DH + d;
        float vv[8];
        #pragma unroll
        for(int jj=0;jj<8;++jj) vv[jj] = vp[(size_t)jj*DH];
        uint4_ pk;
        #pragma unroll
        for(int p2=0;p2<4;++p2)
          pk[p2] = (unsigned)(unsigned short)f2bf(vv[2*p2]) |
                   ((unsigned)(unsigned short)f2bf(vv[2*p2+1])<<16);
        *(uint4_*)&VP[d*VSTf + 4*jg] = pk;
      }
      __syncthreads();
      float4_ sacc[2][2];
      #pragma unroll
      for(int a=0;a<2;++a)
        #pragma unroll
        for(int b=0;b<2;++b) sacc[a][b] = (float4_)0.f;
      #pragma unroll
      for(int ks=0;ks<4;++ks){
        short8 khf[2], klf[2];
        #pragma unroll
        for(int ct=0;ct<2;++ct){
          const int off = (32*wc + 16*ct + lr)*KSTf + 32*ks + 8*quad;
          khf[ct] = *(const short8*)&Khi[off];
          klf[ct] = *(const short8*)&Klo[off];
        }
        #pragma unroll
        for(int rt=0;rt<2;++rt)
          #pragma unroll
          for(int ct=0;ct<2;++ct){
            sacc[rt][ct]=__builtin_amdgcn_mfma_f32_16x16x32_bf16(qhf[rt][ks],khf[ct],sacc[rt][ct],0,0,0);
            sacc[rt][ct]=__builtin_amdgcn_mfma_f32_16x16x32_bf16(qhf[rt][ks],klf[ct],sacc[rt][ct],0,0,0);
            sacc[rt][ct]=__builtin_amdgcn_mfma_f32_16x16x32_bf16(qlf[rt][ks],khf[ct],sacc[rt][ct],0,0,0);
          }
      }
      #pragma unroll
      for(int rt=0;rt<2;++rt){
        float qs[4];
        #pragma unroll
        for(int r=0;r<4;++r) qs[r]=qsq_s[32*wr+16*rt+4*quad+r];
        #pragma unroll
        for(int ct=0;ct<2;++ct){
          const float ksq = ksq_s[32*wc+16*ct+lr];
          const int colg = jc + 32*wc+16*ct+lr;
          #pragma unroll
          for(int r=0;r<4;++r){
            const int rowg = m*64 + 32*wr+16*rt+4*quad+r;
            float logit = (2.f*SM_SCALE)*sacc[rt][ct][r] - qs[r] - ksq;
            float p = (colg<=rowg)? __expf(logit) : 0.f;
            Pfb[(32*wr+16*rt+4*quad+r)*PSTf + 32*wc+16*ct+lr] = f2bf(p);
          }
        }
      }
      __syncthreads();
      #pragma unroll
      for(int ks2=0;ks2<2;++ks2){
        short8 pf[2];
        #pragma unroll
        for(int rt=0;rt<2;++rt)
          pf[rt] = *(const short8*)&Pfb[(32*wr+16*rt+lr)*PSTf + 32*ks2 + 8*quad];
        #pragma unroll
        for(int ctv=0;ctv<4;++ctv){
          const int d = 64*wc + 16*ctv + lr;
          const short8 vfb = *(const short8*)((const short*)VP + d*(2*VSTf) + 32*ks2 + 8*quad);
          #pragma unroll
          for(int rt=0;rt<2;++rt)
            oacc[rt][ctv]=__builtin_amdgcn_mfma_f32_16x16x32_bf16(pf[rt],vfb,oacc[rt][ctv],0,0,0);
        }
      }
    }
    #pragma unroll
    for(int rt=0;rt<2;++rt)
      #pragma unroll
      for(int ctv=0;ctv<4;++ctv)
        #pragma unroll
        for(int r=0;r<4;++r){
          const int rowg = m*64 + 32*wr + 16*rt + 4*quad + r;
          Og[(size_t)rowg*DH + 64*wc + 16*ctv + lr] = oacc[rt][ctv][r];
        }
  }
}

extern "C" void kernel_launch(void* const* d_in, const int* in_sizes, int n_in,
                              void* d_out, int out_size, void* d_ws, size_t ws_size,
                              hipStream_t stream) {
  const float* q = (const float*)d_in[0];
  const float* k = (const float*)d_in[1];
  const float* v = (const float*)d_in[2];
  float* out = (float*)d_out;

  const size_t nElem = (size_t)BHC*NSEQ*DH;            // 8.39M
  const size_t need  = nElem*2*sizeof(short) + (size_t)BHC*NSEQ*sizeof(float);

  if(ws_size >= need){
    _Float16* khg = (_Float16*)d_ws;
    short*    vtg = (short*)(khg + nElem);
    float*    ksqg = (float*)(vtg + nElem);
    prep_kv5<<<2048, 256, 0, stream>>>(k, v, khg, vtg, ksqg);
    rbf_attn13<<<dim3(BHC,32), 256, 0, stream>>>(q, khg, vtg, ksqg, out);
  } else {
    rbf_attn_mfma<<<dim3(BHC,16), 256, 0, stream>>>(q, k, v, out);
  }
}

// Round 10
// 191.532 us; speedup vs baseline: 1.6427x; 1.0083x over previous
//
#include <hip/hip_runtime.h>
#include <math.h>

// RBF-kernel causal attention (gfx950), round 14.
// Prepass: K -> f16 row-major + ksq(=s*|k|^2); V -> bf16 transposed
//          tile-contiguous Vt[bh][jt][128d][64j]. All fully coalesced.
// Main (v14 = v13 + equal-duration persistent blocks + dbuf):
//          9 rounds showed time tracks EFFECTIVE waves, not counters;
//          unequal block durations always drain the tail. v14 makes every
//          block identical: it processes Q-tile pair {31-y, y} in sequence
//          -> (32-y)+(y+1) = 33 j-iters for ALL blocks. Grid (32,16)=512
//          = exactly 2 resident/CU (LDS 66KB dbuf), constant 8 waves/CU,
//          zero drain, dispatch-order-proof. Double-buffered K/V/ksq ->
//          ONE barrier/iter (v10), XOR-swizzled LDS (v13, conflicts
//          halved), 16-row waves + in-register P transpose (v9/v13).

#define NSEQ 2048
#define DH   128
#define BHC  32
#define SM_SCALE 0.08838834764831845f

typedef __attribute__((ext_vector_type(8))) short    short8;   // bf16x8
typedef __attribute__((ext_vector_type(8))) _Float16 half8;    // f16x8
typedef __attribute__((ext_vector_type(4))) short    short4_;
typedef __attribute__((ext_vector_type(4))) float    float4_;
typedef __attribute__((ext_vector_type(4))) unsigned uint4_;
typedef __attribute__((ext_vector_type(2))) unsigned uint2_;

__device__ __forceinline__ short f2bf(float x){
  union{float f; unsigned u;} a; a.f=x;
  unsigned r = a.u + 0x7fffu + ((a.u>>16)&1u);   // RNE
  return (short)(r>>16);
}
__device__ __forceinline__ float bf2f(short h){
  union{float f; unsigned u;} a; a.u=((unsigned)(unsigned short)h)<<16; return a.f;
}
__device__ __forceinline__ unsigned packbf(float a, float b){
  return (unsigned)(unsigned short)f2bf(a) | ((unsigned)(unsigned short)f2bf(b)<<16);
}
__device__ __forceinline__ unsigned cvtpk_bf16(float a, float b){
  unsigned r;
  asm("v_cvt_pk_bf16_f32 %0, %1, %2" : "=v"(r) : "v"(a), "v"(b));
  return r;   // lo16 = bf16(a), hi16 = bf16(b), RNE
}

// (X,Y) = cross-32-lane half swap
__device__ __forceinline__ void qswap32(unsigned A, unsigned B, unsigned &X, unsigned &Y){
  uint2_ r = __builtin_amdgcn_permlane32_swap(A, B, false, false);
  X = r[0]; Y = r[1];
}
// (X,Y) = odd/even 16-row swap
__device__ __forceinline__ void qswap16(unsigned A, unsigned B, unsigned &X, unsigned &Y, int oddq){
#if __has_builtin(__builtin_amdgcn_permlane16_swap)
  uint2_ r = __builtin_amdgcn_permlane16_swap(A, B, false, false);
  X = r[0]; Y = r[1];
#else
  unsigned As = (unsigned)__builtin_amdgcn_ds_swizzle((int)A, 0x401F); // xor lane^16
  unsigned Bs = (unsigned)__builtin_amdgcn_ds_swizzle((int)B, 0x401F);
  X = oddq ? Bs : A;
  Y = oddq ? B  : As;
#endif
}

// ---------------- prepass ----------------
__global__ __launch_bounds__(256)
void prep_kv5(const float* __restrict__ kg, const float* __restrict__ vg,
              _Float16* __restrict__ khg, short* __restrict__ vtg,
              float* __restrict__ ksqg){
  __shared__ unsigned Vls[128*33];   // [d][j2] short2-pairs, stride 33 dw
  const int b = blockIdx.x, t = threadIdx.x;
  const int l = t & 63, wv = t >> 6;
  if(b < 1024){
    // ---- V tile (bh, jt): fp32 rows -> bf16 V^T tile-contiguous ----
    const int bh = b>>5, jt = b&31;
    const float4_* vb4 = (const float4_*)(vg + ((size_t)bh*NSEQ + (size_t)jt*64)*DH);
    #pragma unroll
    for(int i=0;i<8;++i){
      float4_ own = vb4[i*256 + t];
      float4_ par;
      par.x = __shfl_xor(own.x, 32); par.y = __shfl_xor(own.y, 32);
      par.z = __shfl_xor(own.z, 32); par.w = __shfl_xor(own.w, 32);
      const int hi = (l>>5)&1;           // row-parity bit
      unsigned w0 = hi ? packbf(par.z, own.z) : packbf(own.x, par.x);
      unsigned w1 = hi ? packbf(par.w, own.w) : packbf(own.y, par.y);
      const int dd = 4*(t&31) + 2*hi;
      const int j2 = 4*i + wv;           // row-pair index
      Vls[dd*33 + j2]     = w0;
      Vls[(dd+1)*33 + j2] = w1;
    }
    __syncthreads();
    short* outp = vtg + ((size_t)(bh*32 + jt)*DH)*64;
    #pragma unroll
    for(int it=0; it<4; ++it){
      int idx = t + 256*it;              // 0..1023
      int d = idx>>3, slot = idx&7;
      uint4_ o;
      o.x = Vls[d*33 + 4*slot];   o.y = Vls[d*33 + 4*slot+1];
      o.z = Vls[d*33 + 4*slot+2]; o.w = Vls[d*33 + 4*slot+3];
      *(uint4_*)(outp + d*64 + 8*slot) = o;
    }
  } else {
    // ---- K: fp32 -> f16 row-major + ksq ----
    const int kb = b - 1024;             // 64 rows per block
    const float4_* kb4 = (const float4_*)(kg + (size_t)kb*64*DH);
    #pragma unroll
    for(int i=0;i<8;++i){
      float4_ x = kb4[i*256 + t];        // row = 64kb + 8i + (t>>5), d = 4*(t&31)
      const int row = 64*kb + 8*i + (t>>5);
      const int d   = 4*(t&31);
      union{ _Float16 h[4]; uint2_ u; } pk;
      pk.h[0]=(_Float16)x.x; pk.h[1]=(_Float16)x.y;
      pk.h[2]=(_Float16)x.z; pk.h[3]=(_Float16)x.w;
      *(uint2_*)(khg + (size_t)row*DH + d) = pk.u;
      float ss = x.x*x.x + x.y*x.y + x.z*x.z + x.w*x.w;
      ss += __shfl_xor(ss,1);  ss += __shfl_xor(ss,2);
      ss += __shfl_xor(ss,4);  ss += __shfl_xor(ss,8);
      ss += __shfl_xor(ss,16);
      if((l&31)==0) ksqg[row] = SM_SCALE*ss;
    }
  }
}

// ---------------- main kernel (v14) ----------------
// Equal-duration blocks: each processes Q-tiles {31-y, y} sequentially
// (33 iters for every block). Double-buffered swizzled LDS, 1 barrier/iter.
__global__ __launch_bounds__(256,2)
void rbf_attn14(const float* __restrict__ qg,
                const _Float16* __restrict__ khg,
                const short* __restrict__ vtg,
                const float* __restrict__ ksqg,
                float* __restrict__ og){
  __shared__ short Kst[2][64*128];    // 2 x 16KB (phys granule = g ^ (row&7))
  __shared__ short Vst[2][128*64];    // 2 x 16KB (phys granule = g ^ (d&7))
  __shared__ float ksLs[2][64];       // 2 x 256B
  // total 66,048 B -> 2 blocks/CU (= grid residency; constant 8 waves/CU)

  const int tid=threadIdx.x;
  const int w=tid>>6, l=tid&63;
  const int quad=l>>4, lr=l&15;
  const int bh=blockIdx.x;
  const int y=blockIdx.y;                // 0..15

  const float*    Qg = qg   + (size_t)bh*NSEQ*DH;
  const _Float16* Kh = khg  + (size_t)bh*NSEQ*DH;
  const short*    Vt = vtg  + (size_t)bh*32*DH*64;
  const float*    Ks = ksqg + (size_t)bh*NSEQ;
  float*          Og = og   + (size_t)bh*NSEQ*DH;

  #pragma unroll 1
  for(int phase=0; phase<2; ++phase){
    const int mq = phase ? y : (31 - y);   // big tile first
    const int qbase = 64*mq + 16*w;        // wave owns 16 q-rows

    // ---- Q -> f16 B-fragments + qsq ----
    half8 qf[4];
    float qsq;
    {
      const int qrow = qbase + lr;
      const float* qp = Qg + (size_t)qrow*DH + 8*quad;
      float ss=0.f;
      #pragma unroll
      for(int ks=0;ks<4;++ks){
        float4_ a = *(const float4_*)(qp + 32*ks);
        float4_ b = *(const float4_*)(qp + 32*ks + 4);
        half8 h;
        #pragma unroll
        for(int j=0;j<4;++j){
          h[j]   = (_Float16)a[j];
          h[j+4] = (_Float16)b[j];
          ss += a[j]*a[j] + b[j]*b[j];
        }
        qf[ks]=h;
      }
      ss += __shfl_xor(ss,16);
      ss += __shfl_xor(ss,32);
      qsq = SM_SCALE*ss;
    }

    float4_ oacc[8];
    #pragma unroll
    for(int b2=0;b2<8;++b2) oacc[b2] = (float4_)0.f;

    // ---- prologue: stage tile 0 ----
    uint4_ kreg[4], vreg[4];
    float  kqreg = 0.f;
    {
      #pragma unroll
      for(int it=0;it<4;++it){
        int idx = tid + 256*it;
        int row = idx>>4, c = idx&15;
        kreg[it] = *(const uint4_*)(Kh + (size_t)row*DH + 8*c);
        int d = idx>>3, slot = idx&7;
        vreg[it] = *(const uint4_*)(Vt + (size_t)d*64 + 8*slot);
      }
      if(tid<64) kqreg = Ks[tid];
    }
    __syncthreads();                     // prior phase readers done with LDS
    {
      #pragma unroll
      for(int it=0;it<4;++it){
        int idx = tid + 256*it;
        int row = idx>>4, c = idx&15;
        *(uint4_*)&Kst[0][row*128 + 8*(c ^ (row&7))] = kreg[it];
        int d = idx>>3, slot = idx&7;
        *(uint4_*)&Vst[0][d*64 + 8*(slot ^ (d&7))] = vreg[it];
      }
      if(tid<64) ksLs[0][tid] = kqreg;
    }

    int cur = 0;
    for(int jt=0; jt<=mq; ++jt){
      __syncthreads();                   // buf[cur] visible; buf[cur^1] free

      // ---- issue global loads for tile jt+1 ----
      if(jt < mq){
        const int jc2 = (jt+1)*64;
        #pragma unroll
        for(int it=0;it<4;++it){
          int idx = tid + 256*it;
          int row = idx>>4, c = idx&15;
          kreg[it] = *(const uint4_*)(Kh + (size_t)(jc2+row)*DH + 8*c);
          int d = idx>>3, slot = idx&7;
          vreg[it] = *(const uint4_*)(Vt + ((size_t)(jt+1)*DH + d)*64 + 8*slot);
        }
        if(tid<64) kqreg = Ks[jc2 + tid];
      }

      const bool diag = (jt == mq);
      const int ctmax = diag ? w : 3;              // QK tiles with any unmasked col
      const int nks2  = (diag && w < 2) ? 1 : 2;   // PV k-clusters with any P!=0

      // ---- S^T = K . Q^T (f16) ----
      float4_ sacc[4];
      #pragma unroll
      for(int ct=0;ct<4;++ct) sacc[ct] = (float4_)0.f;

      __builtin_amdgcn_s_setprio(1);
      #pragma unroll
      for(int ks=0;ks<4;++ks){
        half8 kf[4];
        #pragma unroll
        for(int ct=0;ct<4;++ct)
          if(ct<=ctmax)
            kf[ct] = *(const half8*)&Kst[cur][(16*ct+lr)*128 + 8*((4*ks+quad) ^ (lr&7))];
        #pragma unroll
        for(int ct=0;ct<4;++ct)
          if(ct<=ctmax) sacc[ct]=__builtin_amdgcn_mfma_f32_16x16x32_f16(kf[ct],qf[ks],sacc[ct],0,0,0);
      }
      __builtin_amdgcn_s_setprio(0);

      // ---- exp -> packed bf16 P in registers ----
      unsigned pk[4][2];
      {
        const int jg0 = 64*jt;
        const int qrow = qbase + lr;
        #pragma unroll
        for(int ct=0;ct<4;++ct){
          if(ct < 2*nks2){
            float4_ kq = *(const float4_*)&ksLs[cur][16*ct + 4*quad];
            const int j0 = jg0 + 16*ct + 4*quad;
            float p[4];
            #pragma unroll
            for(int r=0;r<4;++r){
              float logit = (2.f*SM_SCALE)*sacc[ct][r] - qsq - kq[r];
              p[r] = (j0 + r <= qrow) ? __expf(logit) : 0.f;
            }
            pk[ct][0] = cvtpk_bf16(p[0], p[1]);
            pk[ct][1] = cvtpk_bf16(p[2], p[3]);
          }
        }
      }

      // ---- O += P . V (in-register P transpose) ----
      __builtin_amdgcn_s_setprio(1);
      #pragma unroll
      for(int ks2=0;ks2<2;++ks2){
        if(ks2 < nks2){
          unsigned A0,B0,A1,B1;
          qswap32(pk[2*ks2][0], pk[2*ks2+1][0], A0, B0);
          qswap32(pk[2*ks2][1], pk[2*ks2+1][1], A1, B1);
          unsigned w0,w1,w2,w3;
          qswap16(A0, B0, w0, w2, quad&1);
          qswap16(A1, B1, w1, w3, quad&1);
          union{ uint4_ u; short8 s; } pfu;
          pfu.u.x=w0; pfu.u.y=w1; pfu.u.z=w2; pfu.u.w=w3;
          const short8 pf = pfu.s;   // = P[q=lr][j=32ks2+8quad+e], bf16
          #pragma unroll
          for(int ctv=0;ctv<8;++ctv){
            const short8 vf = *(const short8*)&Vst[cur][(16*ctv+lr)*64 + 8*((4*ks2+quad) ^ (lr&7))];
            oacc[ctv]=__builtin_amdgcn_mfma_f32_16x16x32_bf16(pf,vf,oacc[ctv],0,0,0);
          }
        }
      }
      __builtin_amdgcn_s_setprio(0);

      // ---- write staged regs -> other buffer (no barrier needed) ----
      if(jt < mq){
        const int nxt = cur^1;
        #pragma unroll
        for(int it=0;it<4;++it){
          int idx = tid + 256*it;
          int row = idx>>4, c = idx&15;
          *(uint4_*)&Kst[nxt][row*128 + 8*(c ^ (row&7))] = kreg[it];
          int d = idx>>3, slot = idx&7;
          *(uint4_*)&Vst[nxt][d*64 + 8*(slot ^ (d&7))] = vreg[it];
        }
        if(tid<64) ksLs[nxt][tid] = kqreg;
      }
      cur ^= 1;
    }

    // ---- store O for this phase ----
    #pragma unroll
    for(int ctv=0;ctv<8;++ctv)
      #pragma unroll
      for(int r=0;r<4;++r){
        const int qrow = qbase + 4*quad + r;
        Og[(size_t)qrow*DH + 16*ctv + lr] = oacc[ctv][r];
      }
  }
}

// ---------------- fallback (no-workspace path, verified R2 kernel) ----------------
#define KSTf 136
#define VSTf 36
#define PSTf 72

__global__ __launch_bounds__(256,2)
void rbf_attn_mfma(const float* __restrict__ qg, const float* __restrict__ kg,
                   const float* __restrict__ vg, float* __restrict__ og){
  __shared__ short    Khi[64*KSTf];
  __shared__ short    Klo[64*KSTf];
  __shared__ unsigned VP [128*VSTf];
  __shared__ short    Pfb[64*PSTf];
  __shared__ float    qsq_s[64];
  __shared__ float    ksq_s[64];

  const int tid=threadIdx.x;
  const int w=tid>>6, l=tid&63;
  const int wr=w>>1, wc=w&1;
  const int quad=l>>4, lr=l&15;
  const int bh=blockIdx.x, yp=blockIdx.y;

  const float* Qg = qg + (size_t)bh*NSEQ*DH;
  const float* Kg = kg + (size_t)bh*NSEQ*DH;
  const float* Vg = vg + (size_t)bh*NSEQ*DH;
  float*       Og = og + (size_t)bh*NSEQ*DH;

  for(int pass=0;pass<2;++pass){
    const int m = pass ? (31-yp) : yp;
    __syncthreads();
    short8 qhf[2][4], qlf[2][4];
    #pragma unroll
    for(int rt=0;rt<2;++rt){
      const int grow = m*64 + 32*wr + 16*rt + lr;
      const float* qp = Qg + (size_t)grow*DH + 8*quad;
      float ss=0.f;
      #pragma unroll
      for(int ks=0;ks<4;++ks){
        float4_ a = *(const float4_*)(qp + 32*ks);
        float4_ b = *(const float4_*)(qp + 32*ks + 4);
        short8 hi, lo;
        #pragma unroll
        for(int j=0;j<4;++j){
          float fa=a[j], fb=b[j];
          short ha=f2bf(fa); hi[j]=ha;   lo[j]=f2bf(fa-bf2f(ha));
          short hb=f2bf(fb); hi[j+4]=hb; lo[j+4]=f2bf(fb-bf2f(hb));
          ss += fa*fa + fb*fb;
        }
        qhf[rt][ks]=hi; qlf[rt][ks]=lo;
      }
      ss += __shfl_xor(ss,16);
      ss += __shfl_xor(ss,32);
      if(wc==0 && quad==0) qsq_s[32*wr+16*rt+lr] = SM_SCALE*ss;
    }
    float4_ oacc[2][4];
    #pragma unroll
    for(int a=0;a<2;++a)
      #pragma unroll
      for(int b=0;b<4;++b) oacc[a][b] = (float4_)0.f;

    const int ntiles = m+1;
    for(int jt=0;jt<ntiles;++jt){
      const int jc = jt*64;
      __syncthreads();
      #pragma unroll
      for(int it=0;it<4;++it){
        const int i = tid + 256*it;
        const int row = i>>4, c0 = 8*(i&15);
        const float* kp = Kg + (size_t)(jc+row)*DH + c0;
        float4_ a = *(const float4_*)kp;
        float4_ b = *(const float4_*)(kp+4);
        short8 hi, lo;
        float ss=0.f;
        #pragma unroll
        for(int j=0;j<4;++j){
          float fa=a[j], fb=b[j];
          short ha=f2bf(fa); hi[j]=ha;   lo[j]=f2bf(fa-bf2f(ha));
          short hb=f2bf(fb); hi[j+4]=hb; lo[j+4]=f2bf(fb-bf2f(hb));
          ss += fa*fa + fb*fb;
        }
        ss += __shfl_xor(ss,1); ss += __shfl_xor(ss,2);
        ss += __shfl_xor(ss,4); ss += __shfl_xor(ss,8);
        if(lr==0) ksq_s[row] = SM_SCALE*ss;
        *(short8*)&Khi[row*KSTf + c0] = hi;
        *(short8*)&Klo[row*KSTf + c0] = lo;
      }
      #pragma unroll
      for(int it=0;it<4;++it){
        const int u = tid + 256*it;
        const int d = u & 127, jg = u >> 7;
        const float* vp = Vg + (size_t)(jc + 8*jg)*DH + d;
        float vv[8];
        #pragma unroll
        for(int jj=0;jj<8;++jj) vv[jj] = vp[(size_t)jj*DH];
        uint4_ pk;
        #pragma unroll
        for(int p2=0;p2<4;++p2)
          pk[p2] = (unsigned)(unsigned short)f2bf(vv[2*p2]) |
                   ((unsigned)(unsigned short)f2bf(vv[2*p2+1])<<16);
        *(uint4_*)&VP[d*VSTf + 4*jg] = pk;
      }
      __syncthreads();
      float4_ sacc[2][2];
      #pragma unroll
      for(int a=0;a<2;++a)
        #pragma unroll
        for(int b=0;b<2;++b) sacc[a][b] = (float4_)0.f;
      #pragma unroll
      for(int ks=0;ks<4;++ks){
        short8 khf[2], klf[2];
        #pragma unroll
        for(int ct=0;ct<2;++ct){
          const int off = (32*wc + 16*ct + lr)*KSTf + 32*ks + 8*quad;
          khf[ct] = *(const short8*)&Khi[off];
          klf[ct] = *(const short8*)&Klo[off];
        }
        #pragma unroll
        for(int rt=0;rt<2;++rt)
          #pragma unroll
          for(int ct=0;ct<2;++ct){
            sacc[rt][ct]=__builtin_amdgcn_mfma_f32_16x16x32_bf16(qhf[rt][ks],khf[ct],sacc[rt][ct],0,0,0);
            sacc[rt][ct]=__builtin_amdgcn_mfma_f32_16x16x32_bf16(qhf[rt][ks],klf[ct],sacc[rt][ct],0,0,0);
            sacc[rt][ct]=__builtin_amdgcn_mfma_f32_16x16x32_bf16(qlf[rt][ks],khf[ct],sacc[rt][ct],0,0,0);
          }
      }
      #pragma unroll
      for(int rt=0;rt<2;++rt){
        float qs[4];
        #pragma unroll
        for(int r=0;r<4;++r) qs[r]=qsq_s[32*wr+16*rt+4*quad+r];
        #pragma unroll
        for(int ct=0;ct<2;++ct){
          const float ksq = ksq_s[32*wc+16*ct+lr];
          const int colg = jc + 32*wc+16*ct+lr;
          #pragma unroll
          for(int r=0;r<4;++r){
            const int rowg = m*64 + 32*wr+16*rt+4*quad+r;
            float logit = (2.f*SM_SCALE)*sacc[rt][ct][r] - qs[r] - ksq;
            float p = (colg<=rowg)? __expf(logit) : 0.f;
            Pfb[(32*wr+16*rt+4*quad+r)*PSTf + 32*wc+16*ct+lr] = f2bf(p);
          }
        }
      }
      __syncthreads();
      #pragma unroll
      for(int ks2=0;ks2<2;++ks2){
        short8 pf[2];
        #pragma unroll
        for(int rt=0;rt<2;++rt)
          pf[rt] = *(const short8*)&Pfb[(32*wr+16*rt+lr)*PSTf + 32*ks2 + 8*quad];
        #pragma unroll
        for(int ctv=0;ctv<4;++ctv){
          const int d = 64*wc + 16*ctv + lr;
          const short8 vfb = *(const short8*)((const short*)VP + d*(2*VSTf) + 32*ks2 + 8*quad);
          #pragma unroll
          for(int rt=0;rt<2;++rt)
            oacc[rt][ctv]=__builtin_amdgcn_mfma_f32_16x16x32_bf16(pf[rt],vfb,oacc[rt][ctv],0,0,0);
        }
      }
    }
    #pragma unroll
    for(int rt=0;rt<2;++rt)
      #pragma unroll
      for(int ctv=0;ctv<4;++ctv)
        #pragma unroll
        for(int r=0;r<4;++r){
          const int rowg = m*64 + 32*wr + 16*rt + 4*quad + r;
          Og[(size_t)rowg*DH + 64*wc + 16*ctv + lr] = oacc[rt][ctv][r];
        }
  }
}

extern "C" void kernel_launch(void* const* d_in, const int* in_sizes, int n_in,
                              void* d_out, int out_size, void* d_ws, size_t ws_size,
                              hipStream_t stream) {
  const float* q = (const float*)d_in[0];
  const float* k = (const float*)d_in[1];
  const float* v = (const float*)d_in[2];
  float* out = (float*)d_out;

  const size_t nElem = (size_t)BHC*NSEQ*DH;            // 8.39M
  const size_t need  = nElem*2*sizeof(short) + (size_t)BHC*NSEQ*sizeof(float);

  if(ws_size >= need){
    _Float16* khg = (_Float16*)d_ws;
    short*    vtg = (short*)(khg + nElem);
    float*    ksqg = (float*)(vtg + nElem);
    prep_kv5<<<2048, 256, 0, stream>>>(k, v, khg, vtg, ksqg);
    rbf_attn14<<<dim3(BHC,16), 256, 0, stream>>>(q, khg, vtg, ksqg, out);
  } else {
    rbf_attn_mfma<<<dim3(BHC,16), 256, 0, stream>>>(q, k, v, out);
  }
}